// Round 8
// baseline (84.045 us; speedup 1.0000x reference)
//
#include <hip/hip_runtime.h>

#define DIM   4096
#define RANK  16
#define BM    16     // rows per block = MFMA M
#define NT    512    // 8 waves
#define NWAVE 8
#define KTILE 512              // k-floats per staged tile
#define NTILE (DIM/KTILE)      // 8
#define XPAD  516              // xbuf row stride (floats): 16B-aligned, odd float4
#define NCB   (DIM/16/NWAVE)   // 32 out col-blocks per wave in phase B

typedef __fp16 f16;
typedef __fp16 half4 __attribute__((ext_vector_type(4)));
typedef __fp16 half8 __attribute__((ext_vector_type(8)));
typedef float  floatx4 __attribute__((ext_vector_type(4)));

// counted vmcnt wait + scheduling fence (rule #18)
#define VM_WAIT0 { asm volatile("s_waitcnt vmcnt(0)" ::: "memory"); \
                   __builtin_amdgcn_sched_barrier(0); }

// async global->LDS DMA, 16 B per lane; LDS dest = uniform base + lane*16
__device__ __forceinline__ void gld16(const void* g, void* l) {
    __builtin_amdgcn_global_load_lds((__attribute__((address_space(1))) void*)g,
                                     (__attribute__((address_space(3))) void*)l,
                                     16, 0, 0);
}

// ---- prep: weights in exact MFMA fragment order ----
// A/B fragment mapping (16x16xK): lane&15 = row(A)/col(B), lane>>4 = k-block.
// Ub[kb][l][e] = nw[k]*U[k][l&15],          k = kb*32 + (l>>4)*8 + e   (128 KB)
// Vb[cb][l][e] = V[(l>>4)*4 + e][cb*16+l&15]                           (128 KB)
__global__ __launch_bounds__(256) void prep_weights(const float* __restrict__ U,
    const float* __restrict__ nw, const float* __restrict__ V,
    f16* __restrict__ Ub, f16* __restrict__ Vb)
{
    const int i   = blockIdx.x * 256 + threadIdx.x;   // 0..16383
    const int l   = i & 63;
    const int n   = l & 15;
    const int blk = l >> 4;
    if (i < 8192) {                     // Ub: 128 kb-steps x 64 lanes
        const int kb = i >> 6;
        half8 u;
        #pragma unroll
        for (int e = 0; e < 8; ++e) {
            const int k = kb * 32 + blk * 8 + e;
            u[e] = (f16)(nw[k] * U[(size_t)k * RANK + n]);
        }
        *(half8*)(Ub + (size_t)i * 8) = u;      // 16 B coalesced
    }
    {                                   // Vb: 256 col-blocks x 64 lanes
        const int cb = i >> 6;
        half4 v;
        #pragma unroll
        for (int e = 0; e < 4; ++e) {
            const int k = blk * 4 + e;
            v[e] = (f16)V[(size_t)k * DIM + cb * 16 + n];
        }
        *(half4*)(Vb + (size_t)i * 4) = v;      // 8 B coalesced
    }
}

// ---- fused kernel ----
// Phase A: m97-style tile pipeline. Per K-tile: 32 KB of x staged by 32 fully
// CONTIGUOUS 1 KB global_load_lds (wave w -> rows 2w,2w+1), double-buffered;
// issue(t+1) right after the barrier so a whole tile is in flight across the
// consume + wait window. 2 blocks/CU interleave to keep HBM streaming.
// Phase B: operand-swapped MFMA -> float4 residual/store per lane (R7).
__global__ __launch_bounds__(NT, 4) void arl_fused(
    const float* __restrict__ x,  const f16* __restrict__ Ub,
    const f16* __restrict__ Vb,   const float* __restrict__ S,
    const float* __restrict__ gamma, float* __restrict__ out)
{
    const int t   = threadIdx.x;
    const int w   = t >> 6;
    const int l   = t & 63;
    const int n   = l & 15;     // A-frag row / B,D-frag col
    const int blk = l >> 4;     // k-block / D row-group
    const size_t row0 = (size_t)blockIdx.x * BM;

    __shared__ __align__(16) float xbuf[2][BM][XPAD];   // 66 KB (padded rows)
    __shared__ float s_hacc[NWAVE][16][17];             // 8.7 KB (+1 pad)
    __shared__ float s_ssq[NWAVE][16];
    __shared__ __align__(8) f16 s_hh[16][16];

    const float* xg   = x + row0 * DIM;
    const int    srow = 2 * w;          // wave's staging rows: srow, srow+1

    // ================= Phase A: acc[m][q] += x[m][k]*U'[k][q] =================
    floatx4 acc = {0.f, 0.f, 0.f, 0.f};
    float ssq = 0.f;

    // prologue: tile 0 -> buf 0 (4 contiguous 1 KB DMA per wave)
    #pragma unroll
    for (int j = 0; j < 4; ++j) {
        const int row  = srow + (j >> 1);
        const int half = j & 1;
        gld16(xg + (size_t)row * DIM + half * 256 + l * 4,
              &xbuf[0][row][half * 256]);
    }

    int cur = 0;
    #pragma unroll 1
    for (int tt = 0; tt < NTILE; ++tt) {
        VM_WAIT0;                       // this wave's share of tile tt landed
        __syncthreads();                // all shares landed; buf^1 consumers done
        if (tt + 1 < NTILE) {           // issue tile tt+1 -> in flight during
            #pragma unroll              // consume + next wait (32 KB/block)
            for (int j = 0; j < 4; ++j) {
                const int row  = srow + (j >> 1);
                const int half = j & 1;
                gld16(xg + (size_t)row * DIM + (size_t)(tt + 1) * KTILE
                          + half * 256 + l * 4,
                      &xbuf[cur ^ 1][row][half * 256]);
            }
        }
        // consume: wave w owns k-sub [w*64, w*64+64) of this tile = 2 MFMA steps
        #pragma unroll
        for (int s = 0; s < 2; ++s) {
            const int koff = w * 64 + s * 32 + blk * 8;
            const float4 xa0 = *(const float4*)&xbuf[cur][n][koff];
            const float4 xa1 = *(const float4*)&xbuf[cur][n][koff + 4];
            const int kb = tt * (KTILE / 32) + w * 2 + s;
            const half8 ub = *(const half8*)(Ub + ((size_t)kb * 64 + l) * 8);
            ssq = fmaf(xa0.x, xa0.x, ssq); ssq = fmaf(xa0.y, xa0.y, ssq);
            ssq = fmaf(xa0.z, xa0.z, ssq); ssq = fmaf(xa0.w, xa0.w, ssq);
            ssq = fmaf(xa1.x, xa1.x, ssq); ssq = fmaf(xa1.y, xa1.y, ssq);
            ssq = fmaf(xa1.z, xa1.z, ssq); ssq = fmaf(xa1.w, xa1.w, ssq);
            half8 a;
            a[0] = (f16)xa0.x; a[1] = (f16)xa0.y; a[2] = (f16)xa0.z; a[3] = (f16)xa0.w;
            a[4] = (f16)xa1.x; a[5] = (f16)xa1.y; a[6] = (f16)xa1.z; a[7] = (f16)xa1.w;
            acc = __builtin_amdgcn_mfma_f32_16x16x32_f16(a, ub, acc, 0, 0, 0);
        }
        cur ^= 1;
    }

    // ssq: sum the 4 k-block lane groups sharing a row (l, l^16, l^32, l^48)
    ssq += __shfl_xor(ssq, 16, 64);
    ssq += __shfl_xor(ssq, 32, 64);
    if (l < 16) s_ssq[w][l] = ssq;

    // spill C-fragment: D[m = blk*4+j][q = n]
    #pragma unroll
    for (int j = 0; j < 4; ++j) s_hacc[w][blk * 4 + j][n] = acc[j];
    __syncthreads();

    // ============ combine waves; fold rstd + S*keep; publish h (f16) ============
    if (t < 256) {
        const int m = t >> 4, q = t & 15;
        float hsum = 0.f, tssq = 0.f;
        #pragma unroll
        for (int ww = 0; ww < NWAVE; ++ww) {
            hsum += s_hacc[ww][m][q];
            tssq += s_ssq[ww][m];
        }
        const float rstd = rsqrtf(tssq * (1.0f / DIM) + 1e-6f);
        float tot = 0.f;
        #pragma unroll
        for (int i = 0; i < RANK; ++i) tot += fabsf(S[i]);
        const float denom = fmaxf(tot, 1e-8f);
        float cum = 0.f, se = 0.f;
        #pragma unroll
        for (int i = 0; i < RANK; ++i) {
            if (i == q) se = ((cum / denom) < 0.95f) ? S[i] : 0.f;
            cum += fabsf(S[i]);
        }
        s_hh[m][q] = (f16)(hsum * se * rstd);
    }
    __syncthreads();

    // ================= Phase B: out = x + gamma * (h . V) =================
    // Operand swap: D' = mfma(bv, ah): lane owns out[row0+n][c0..c0+4) ->
    // single float4 residual load + float4 nontemporal store per iter.
    const half4 ah = *(const half4*)&s_hh[n][blk * 4];    // h[n][blk*4..+4)
    const half4* Vb4 = (const half4*)Vb;
    const floatx4 zero = {0.f, 0.f, 0.f, 0.f};
    const float* xrow = x   + (row0 + n) * DIM;
    float*       orow = out + (row0 + n) * DIM;

    #pragma unroll 4
    for (int i = 0; i < NCB; ++i) {
        const int cb = w * NCB + i;
        const int c0 = cb * 16 + blk * 4;
        const half4 bv = Vb4[(size_t)cb * 64 + l];          // 8 B coalesced, L2-hot
        floatx4 d = __builtin_amdgcn_mfma_f32_16x16x16f16(bv, ah, zero, 0, 0, 0);
        const float4 g  = *(const float4*)(gamma + c0);     // L1-hot broadcast
        const float4 xv = *(const float4*)(xrow + c0);      // L3-hot residual
        floatx4 o;
        o[0] = fmaf(g.x, d[0], xv.x);
        o[1] = fmaf(g.y, d[1], xv.y);
        o[2] = fmaf(g.z, d[2], xv.z);
        o[3] = fmaf(g.w, d[3], xv.w);
        __builtin_nontemporal_store(o, (floatx4*)(orow + c0));
    }
}

extern "C" void kernel_launch(void* const* d_in, const int* in_sizes, int n_in,
                              void* d_out, int out_size, void* d_ws, size_t ws_size,
                              hipStream_t stream) {
    (void)in_sizes; (void)n_in; (void)ws_size;
    const float* x  = (const float*)d_in[0];
    const float* U  = (const float*)d_in[1];
    const float* S  = (const float*)d_in[2];
    const float* V  = (const float*)d_in[3];
    const float* nw = (const float*)d_in[4];
    const float* g  = (const float*)d_in[5];
    float* out = (float*)d_out;
    f16* Ub = (f16*)d_ws;                          // 128 KB fragment-order U'
    f16* Vb = (f16*)((char*)d_ws + 128 * 1024);    // 128 KB fragment-order V

    hipLaunchKernelGGL(prep_weights, dim3(64), dim3(256), 0, stream,
                       U, nw, V, Ub, Vb);

    const int rows = out_size / DIM;               // 8192
    const int grid = rows / BM;                    // 512
    hipLaunchKernelGGL(arl_fused, dim3(grid), dim3(NT), 0, stream,
                       x, Ub, Vb, S, g, out);
}

// Round 9
// 78.318 us; speedup vs baseline: 1.0731x; 1.0731x over previous
//
#include <hip/hip_runtime.h>

#define DIM   4096
#define RANK  16
#define BM    16     // rows per block tile = MFMA M
#define NT    512    // 8 waves
#define NWAVE 8

typedef __fp16 f16;
typedef __fp16 half4 __attribute__((ext_vector_type(4)));
typedef __fp16 half8 __attribute__((ext_vector_type(8)));
typedef float  floatx4 __attribute__((ext_vector_type(4)));

// ---- prep: weights in exact MFMA fragment order ----
// A/B fragment mapping (16x16xK): lane&15 = row(A)/col(B), lane>>4 = k-block.
// Ub[kb][l][e] = nw[k]*U[k][l&15],          k = kb*32 + (l>>4)*8 + e   (128 KB)
// Vb[cb][l][e] = V[(l>>4)*4 + e][cb*16+l&15]                           (128 KB)
__global__ __launch_bounds__(256) void prep_weights(const float* __restrict__ U,
    const float* __restrict__ nw, const float* __restrict__ V,
    f16* __restrict__ Ub, f16* __restrict__ Vb)
{
    const int i   = blockIdx.x * 256 + threadIdx.x;   // 0..16383
    const int l   = i & 63;
    const int n   = l & 15;
    const int blk = l >> 4;
    if (i < 8192) {                     // Ub: 128 kb-steps x 64 lanes
        const int kb = i >> 6;
        half8 u;
        #pragma unroll
        for (int e = 0; e < 8; ++e) {
            const int k = kb * 32 + blk * 8 + e;
            u[e] = (f16)(nw[k] * U[(size_t)k * RANK + n]);
        }
        *(half8*)(Ub + (size_t)i * 8) = u;      // 16 B coalesced
    }
    {                                   // Vb: 256 col-blocks x 64 lanes
        const int cb = i >> 6;
        half4 v;
        #pragma unroll
        for (int e = 0; e < 4; ++e) {
            const int k = blk * 4 + e;
            v[e] = (f16)V[(size_t)k * DIM + cb * 16 + n];
        }
        *(half4*)(Vb + (size_t)i * 4) = v;      // 8 B coalesced
    }
}

// ---- Kernel A: pure read stream. hraw[row][slot][q], ssqg[row][slot] ----
// grid 1024 = (rows/16) x 2 k-halves; 8 waves; LDS 9.2 KB; 4 blocks/CU ->
// 32 waves/CU. Latency hidden by TLP (fill-kernel math: 32 waves x ~1KB
// outstanding >> 9.3 KB BW*latency product), not by hand pipelining.
__global__ __launch_bounds__(NT, 8) void arl_dots(
    const float* __restrict__ x,  const f16* __restrict__ Ub,
    f16* __restrict__ hraw, float* __restrict__ ssqg)
{
    const int t   = threadIdx.x;
    const int w   = t >> 6;
    const int l   = t & 63;
    const int n   = l & 15;     // A-frag row
    const int blk = l >> 4;     // k-block within MFMA step
    const int bid = blockIdx.x;
    const size_t row0 = (size_t)(bid >> 1) * BM;
    const int    bk   = bid & 1;          // k-half: [bk*2048, bk*2048+2048)

    __shared__ float s_hacc[NWAVE][16][17];   // 8.7 KB (+1 pad)
    __shared__ float s_ssq[NWAVE][16];

    // wave w owns k-sub [bk*2048 + w*256, +256) = 8 MFMA k-steps
    const float* xlane = x + (row0 + n) * DIM + bk * 2048 + w * 256 + blk * 8;
    const f16*   UbW   = Ub + (((size_t)(bk * 64 + w * 8)) * 64 + l) * 8;

    floatx4 acc = {0.f, 0.f, 0.f, 0.f};
    float ssq = 0.f;

    #pragma unroll
    for (int s = 0; s < 8; ++s) {
        const float4 xa0 = *(const float4*)(xlane + s * 32);
        const float4 xa1 = *(const float4*)(xlane + s * 32 + 4);
        const half8  ub  = *(const half8*)(UbW + (size_t)s * 512);
        ssq = fmaf(xa0.x, xa0.x, ssq); ssq = fmaf(xa0.y, xa0.y, ssq);
        ssq = fmaf(xa0.z, xa0.z, ssq); ssq = fmaf(xa0.w, xa0.w, ssq);
        ssq = fmaf(xa1.x, xa1.x, ssq); ssq = fmaf(xa1.y, xa1.y, ssq);
        ssq = fmaf(xa1.z, xa1.z, ssq); ssq = fmaf(xa1.w, xa1.w, ssq);
        half8 a;
        a[0] = (f16)xa0.x; a[1] = (f16)xa0.y; a[2] = (f16)xa0.z; a[3] = (f16)xa0.w;
        a[4] = (f16)xa1.x; a[5] = (f16)xa1.y; a[6] = (f16)xa1.z; a[7] = (f16)xa1.w;
        acc = __builtin_amdgcn_mfma_f32_16x16x32_f16(a, ub, acc, 0, 0, 0);
    }

    // ssq: sum the 4 k-block lane groups sharing a row (l, l^16, l^32, l^48)
    ssq += __shfl_xor(ssq, 16, 64);
    ssq += __shfl_xor(ssq, 32, 64);
    if (l < 16) s_ssq[w][l] = ssq;

    // spill C-fragment: D[m = blk*4+j][q = n]
    #pragma unroll
    for (int j = 0; j < 4; ++j) s_hacc[w][blk * 4 + j][n] = acc[j];
    __syncthreads();

    // combine 8 waves -> per-slot partials (fold happens in kernel B)
    if (t < 256) {
        const int m = t >> 4, q = t & 15;
        float hsum = 0.f, tssq = 0.f;
        #pragma unroll
        for (int ww = 0; ww < NWAVE; ++ww) {
            hsum += s_hacc[ww][m][q];
            tssq += s_ssq[ww][m];
        }
        hraw[((row0 + m) * 2 + bk) * RANK + q] = (f16)hsum;
        if (q == 0) ssqg[(row0 + m) * 2 + bk] = tssq;
    }
}

// ---- Kernel B: pure write stream. out = x + gamma * (h . V) ----
// grid 1024 = (rows/16) x 2 col-halves; LDS 512 B; 32 waves/CU. Prologue folds
// rstd + S*keep from the 2 k-slot partials; loop = R7's swapped-operand MFMA:
// lane owns out[row0+n][c0..c0+4) -> float4 residual (L3-hot) + float4 NT store.
__global__ __launch_bounds__(NT, 8) void arl_apply(
    const float* __restrict__ x,   const f16* __restrict__ Vb,
    const f16* __restrict__ hraw,  const float* __restrict__ ssqg,
    const float* __restrict__ S,   const float* __restrict__ gamma,
    float* __restrict__ out)
{
    const int t   = threadIdx.x;
    const int w   = t >> 6;
    const int l   = t & 63;
    const int n   = l & 15;     // D-frag col = out row index
    const int blk = l >> 4;     // D-frag row group = out col offset
    const int bid = blockIdx.x;
    const size_t row0 = (size_t)(bid >> 1) * BM;
    const int    bk   = bid & 1;          // col-half: cb in [bk*128, bk*128+128)

    __shared__ __align__(8) f16 s_hh[16][16];

    if (t < 256) {
        const int m = t >> 4, q = t & 15;
        const size_t r = row0 + m;
        const float hs = (float)hraw[(r * 2 + 0) * RANK + q]
                       + (float)hraw[(r * 2 + 1) * RANK + q];
        const float tssq = ssqg[r * 2 + 0] + ssqg[r * 2 + 1];
        const float rstd = rsqrtf(tssq * (1.0f / DIM) + 1e-6f);
        float tot = 0.f;
        #pragma unroll
        for (int i = 0; i < RANK; ++i) tot += fabsf(S[i]);
        const float denom = fmaxf(tot, 1e-8f);
        float cum = 0.f, se = 0.f;
        #pragma unroll
        for (int i = 0; i < RANK; ++i) {
            if (i == q) se = ((cum / denom) < 0.95f) ? S[i] : 0.f;
            cum += fabsf(S[i]);
        }
        s_hh[m][q] = (f16)(hs * se * rstd);
    }
    __syncthreads();

    const half4 ah = *(const half4*)&s_hh[n][blk * 4];    // h[n][blk*4..+4)
    const half4* Vb4 = (const half4*)Vb;
    const floatx4 zero = {0.f, 0.f, 0.f, 0.f};
    const float* xrow = x   + (row0 + n) * DIM;
    float*       orow = out + (row0 + n) * DIM;

    #pragma unroll 4
    for (int i = 0; i < 16; ++i) {
        const int cb = bk * 128 + w * 16 + i;
        const int c0 = cb * 16 + blk * 4;
        const half4 bv = Vb4[(size_t)cb * 64 + l];          // 8 B coalesced, L2-hot
        floatx4 d = __builtin_amdgcn_mfma_f32_16x16x16f16(bv, ah, zero, 0, 0, 0);
        const float4 g  = *(const float4*)(gamma + c0);     // L1-hot broadcast
        const float4 xv = *(const float4*)(xrow + c0);      // L3-hot residual
        floatx4 o;
        o[0] = fmaf(g.x, d[0], xv.x);
        o[1] = fmaf(g.y, d[1], xv.y);
        o[2] = fmaf(g.z, d[2], xv.z);
        o[3] = fmaf(g.w, d[3], xv.w);
        __builtin_nontemporal_store(o, (floatx4*)(orow + c0));
    }
}

extern "C" void kernel_launch(void* const* d_in, const int* in_sizes, int n_in,
                              void* d_out, int out_size, void* d_ws, size_t ws_size,
                              hipStream_t stream) {
    (void)in_sizes; (void)n_in; (void)ws_size;
    const float* x  = (const float*)d_in[0];
    const float* U  = (const float*)d_in[1];
    const float* S  = (const float*)d_in[2];
    const float* V  = (const float*)d_in[3];
    const float* nw = (const float*)d_in[4];
    const float* g  = (const float*)d_in[5];
    float* out = (float*)d_out;
    f16*   Ub   = (f16*)d_ws;                               // 128 KB
    f16*   Vb   = (f16*)((char*)d_ws + 128 * 1024);         // 128 KB
    f16*   hraw = (f16*)((char*)d_ws + 256 * 1024);         // 512 KB (8192*2*16*2B)
    float* ssqg = (float*)((char*)d_ws + 768 * 1024);       // 64 KB  (8192*2*4B)

    hipLaunchKernelGGL(prep_weights, dim3(64), dim3(256), 0, stream,
                       U, nw, V, Ub, Vb);

    const int rows = out_size / DIM;               // 8192
    const int grid = (rows / BM) * 2;              // 1024
    hipLaunchKernelGGL(arl_dots, dim3(grid), dim3(NT), 0, stream,
                       x, Ub, hraw, ssqg);
    hipLaunchKernelGGL(arl_apply, dim3(grid), dim3(NT), 0, stream,
                       x, Vb, hraw, ssqg, S, g, out);
}

// Round 10
// 74.650 us; speedup vs baseline: 1.1259x; 1.0491x over previous
//
#include <hip/hip_runtime.h>

#define DIM   4096
#define RANK  16
#define BM    16     // rows per block = MFMA M
#define NT    512    // 8 waves
#define NWAVE 8
#define NST   8      // sub-tiles per wave (k-slice 512 = 8 x 64 floats)

typedef __fp16 f16;
typedef __fp16 half4 __attribute__((ext_vector_type(4)));
typedef __fp16 half8 __attribute__((ext_vector_type(8)));
typedef float  floatx4 __attribute__((ext_vector_type(4)));

// counted vmcnt wait + scheduling fence (rule #18)
#define VM_WAIT(N) { asm volatile("s_waitcnt vmcnt(" #N ")" ::: "memory"); \
                     __builtin_amdgcn_sched_barrier(0); }
#define SCHED_FENCE() __builtin_amdgcn_sched_barrier(0)

// async global->LDS DMA, 16 B per lane; LDS dest = uniform base + lane*16
__device__ __forceinline__ void gld16(const void* g, void* l) {
    __builtin_amdgcn_global_load_lds((__attribute__((address_space(1))) void*)g,
                                     (__attribute__((address_space(3))) void*)l,
                                     16, 0, 0);
}

// ---- prep: weights in exact MFMA fragment order ----
// A/B fragment mapping (16x16xK): lane&15 = row(A)/col(B), lane>>4 = k-block.
// Ub[kb][l][e] = nw[k]*U[k][l&15],          k = kb*32 + (l>>4)*8 + e   (128 KB)
// Vb[cb][l][e] = V[(l>>4)*4 + e][cb*16+l&15]                           (128 KB)
__global__ __launch_bounds__(256) void prep_weights(const float* __restrict__ U,
    const float* __restrict__ nw, const float* __restrict__ V,
    f16* __restrict__ Ub, f16* __restrict__ Vb)
{
    const int i   = blockIdx.x * 256 + threadIdx.x;   // 0..16383
    const int l   = i & 63;
    const int n   = l & 15;
    const int blk = l >> 4;
    if (i < 8192) {                     // Ub: 128 kb-steps x 64 lanes
        const int kb = i >> 6;
        half8 u;
        #pragma unroll
        for (int e = 0; e < 8; ++e) {
            const int k = kb * 32 + blk * 8 + e;
            u[e] = (f16)(nw[k] * U[(size_t)k * RANK + n]);
        }
        *(half8*)(Ub + (size_t)i * 8) = u;      // 16 B coalesced
    }
    {                                   // Vb: 256 col-blocks x 64 lanes
        const int cb = i >> 6;
        half4 v;
        #pragma unroll
        for (int e = 0; e < 4; ++e) {
            const int k = blk * 4 + e;
            v[e] = (f16)V[(size_t)k * DIM + cb * 16 + n];
        }
        *(half4*)(Vb + (size_t)i * 4) = v;      // 8 B coalesced
    }
}

// ---- fused kernel ----
// Phase A: per-wave self-sufficient DMA pipeline. Wave w stages its own
// k-slice in 4 KB sub-tiles (4 x global_load_lds), double-buffered, NO
// barriers; counted vmcnt(6) keeps the next sub-tile + Ub loads in flight
// (never drains). Source addresses pre-swizzled (granule ^ row&7) so the
// swizzled ds_read_b128 is 2-way-conflict-free (rule #21 both-sides pattern).
// Phase B: swapped-operand MFMA -> float4 residual + float4 NT store (R7).
__global__ __launch_bounds__(NT, 4) void arl_fused(
    const float* __restrict__ x,  const f16* __restrict__ Ub,
    const f16* __restrict__ Vb,   const float* __restrict__ S,
    const float* __restrict__ gamma, float* __restrict__ out)
{
    const int t   = threadIdx.x;
    const int w   = t >> 6;
    const int l   = t & 63;
    const int n   = l & 15;     // A-frag row / B,D-frag col
    const int blk = l >> 4;     // k-block / D row-group
    const size_t row0 = (size_t)blockIdx.x * BM;

    __shared__ __align__(16) float ring[NWAVE][2][BM * 64];   // 64 KB
    __shared__ float s_hacc[NWAVE][16][17];                   // 8.7 KB (+1 pad)
    __shared__ float s_ssq[NWAVE][16];
    __shared__ __align__(8) f16 s_hh[16][16];

    const float* xg = x + row0 * DIM + w * 512;   // wave's k-slice base

    // ================= Phase A: acc[m][q] += x[m][k]*U'[k][q] =================
    floatx4 acc = {0.f, 0.f, 0.f, 0.f};
    float ssq = 0.f;

    // prologue: sub-tile 0 -> buf 0. DMA inst j stages rows 4j..4j+3 (1 KB,
    // contiguous cache lines; 16B granules permuted by the swizzle).
    #pragma unroll
    for (int j = 0; j < 4; ++j) {
        const int rl  = 4 * j + (l >> 4);
        const int gsw = (l & 15) ^ (rl & 7);
        gld16(xg + (size_t)rl * DIM + gsw * 4, &ring[w][0][j * 256]);
    }

    #pragma unroll 1
    for (int st = 0; st < NST; ++st) {
        // Ub for this sub-tile's 2 k-steps: issue BEFORE next DMAs so the
        // compiler's wait-for-ub lands at vmcnt(4), not 0 (FIFO order).
        const int kb0 = w * 16 + st * 2;
        const half8 ub0 = *(const half8*)(Ub + ((size_t)kb0 * 64 + l) * 8);
        const half8 ub1 = *(const half8*)(Ub + ((size_t)(kb0 + 1) * 64 + l) * 8);
        SCHED_FENCE();
        if (st + 1 < NST) {             // issue st+1 -> 6 outstanding after wait
            #pragma unroll
            for (int j = 0; j < 4; ++j) {
                const int rl  = 4 * j + (l >> 4);
                const int gsw = (l & 15) ^ (rl & 7);
                gld16(xg + (size_t)rl * DIM + (st + 1) * 64 + gsw * 4,
                      &ring[w][(st + 1) & 1][j * 256]);
            }
            VM_WAIT(6)                  // st's 4 DMAs retired; st+1 + ub in flight
        } else {
            VM_WAIT(2)                  // last: only ub may remain outstanding
        }

        const float* buf = ring[w][st & 1];
        #pragma unroll
        for (int s = 0; s < 2; ++s) {
            const int g0 = (s * 8 + blk * 2)     ^ (n & 7);   // swizzled granule
            const int g1 = (s * 8 + blk * 2 + 1) ^ (n & 7);
            const float4 xa0 = *(const float4*)&buf[n * 64 + g0 * 4];
            const float4 xa1 = *(const float4*)&buf[n * 64 + g1 * 4];
            ssq = fmaf(xa0.x, xa0.x, ssq); ssq = fmaf(xa0.y, xa0.y, ssq);
            ssq = fmaf(xa0.z, xa0.z, ssq); ssq = fmaf(xa0.w, xa0.w, ssq);
            ssq = fmaf(xa1.x, xa1.x, ssq); ssq = fmaf(xa1.y, xa1.y, ssq);
            ssq = fmaf(xa1.z, xa1.z, ssq); ssq = fmaf(xa1.w, xa1.w, ssq);
            half8 a;
            a[0] = (f16)xa0.x; a[1] = (f16)xa0.y; a[2] = (f16)xa0.z; a[3] = (f16)xa0.w;
            a[4] = (f16)xa1.x; a[5] = (f16)xa1.y; a[6] = (f16)xa1.z; a[7] = (f16)xa1.w;
            acc = __builtin_amdgcn_mfma_f32_16x16x32_f16(a, s ? ub1 : ub0, acc, 0, 0, 0);
        }
    }

    // ssq: sum the 4 k-block lane groups sharing a row (l, l^16, l^32, l^48)
    ssq += __shfl_xor(ssq, 16, 64);
    ssq += __shfl_xor(ssq, 32, 64);
    if (l < 16) s_ssq[w][l] = ssq;

    // spill C-fragment: D[m = blk*4+j][q = n]
    #pragma unroll
    for (int j = 0; j < 4; ++j) s_hacc[w][blk * 4 + j][n] = acc[j];
    __syncthreads();

    // ============ combine waves; fold rstd + S*keep; publish h (f16) ============
    if (t < 256) {
        const int m = t >> 4, q = t & 15;
        float hsum = 0.f, tssq = 0.f;
        #pragma unroll
        for (int ww = 0; ww < NWAVE; ++ww) {
            hsum += s_hacc[ww][m][q];
            tssq += s_ssq[ww][m];
        }
        const float rstd = rsqrtf(tssq * (1.0f / DIM) + 1e-6f);
        float tot = 0.f;
        #pragma unroll
        for (int i = 0; i < RANK; ++i) tot += fabsf(S[i]);
        const float denom = fmaxf(tot, 1e-8f);
        float cum = 0.f, se = 0.f;
        #pragma unroll
        for (int i = 0; i < RANK; ++i) {
            if (i == q) se = ((cum / denom) < 0.95f) ? S[i] : 0.f;
            cum += fabsf(S[i]);
        }
        s_hh[m][q] = (f16)(hsum * se * rstd);
    }
    __syncthreads();

    // ================= Phase B: out = x + gamma * (h . V) =================
    // Operand swap: D' = mfma(bv, ah): lane owns out[row0+n][c0..c0+4) ->
    // single float4 residual load (L3-hot) + float4 nontemporal store.
    const half4 ah = *(const half4*)&s_hh[n][blk * 4];    // h[n][blk*4..+4)
    const half4* Vb4 = (const half4*)Vb;
    const floatx4 zero = {0.f, 0.f, 0.f, 0.f};
    const float* xrow = x   + (row0 + n) * DIM;
    float*       orow = out + (row0 + n) * DIM;

    #pragma unroll 4
    for (int i = 0; i < 32; ++i) {
        const int cb = w * 32 + i;
        const int c0 = cb * 16 + blk * 4;
        const half4 bv = Vb4[(size_t)cb * 64 + l];          // 8 B coalesced, L2-hot
        floatx4 d = __builtin_amdgcn_mfma_f32_16x16x16f16(bv, ah, zero, 0, 0, 0);
        const float4 g  = *(const float4*)(gamma + c0);     // L1-hot broadcast
        const float4 xv = *(const float4*)(xrow + c0);      // L3-hot residual
        floatx4 o;
        o[0] = fmaf(g.x, d[0], xv.x);
        o[1] = fmaf(g.y, d[1], xv.y);
        o[2] = fmaf(g.z, d[2], xv.z);
        o[3] = fmaf(g.w, d[3], xv.w);
        __builtin_nontemporal_store(o, (floatx4*)(orow + c0));
    }
}

extern "C" void kernel_launch(void* const* d_in, const int* in_sizes, int n_in,
                              void* d_out, int out_size, void* d_ws, size_t ws_size,
                              hipStream_t stream) {
    (void)in_sizes; (void)n_in; (void)ws_size;
    const float* x  = (const float*)d_in[0];
    const float* U  = (const float*)d_in[1];
    const float* S  = (const float*)d_in[2];
    const float* V  = (const float*)d_in[3];
    const float* nw = (const float*)d_in[4];
    const float* g  = (const float*)d_in[5];
    float* out = (float*)d_out;
    f16* Ub = (f16*)d_ws;                          // 128 KB fragment-order U'
    f16* Vb = (f16*)((char*)d_ws + 128 * 1024);    // 128 KB fragment-order V

    hipLaunchKernelGGL(prep_weights, dim3(64), dim3(256), 0, stream,
                       U, nw, V, Ub, Vb);

    const int rows = out_size / DIM;               // 8192
    const int grid = rows / BM;                    // 512
    hipLaunchKernelGGL(arl_fused, dim3(grid), dim3(NT), 0, stream,
                       x, Ub, Vb, S, g, out);
}